// Round 1
// baseline (214.393 us; speedup 1.0000x reference)
//
#include <hip/hip_runtime.h>

#define GRID_N 112
#define O_MAX 48
#define HW_N (GRID_N * GRID_N)
#define NTHREADS 256

// channel[b,h,w] = 0.5 + 0.5*gx[h]*gy[w] - 0.5*sum_o ex[o,h]*ey[o,w]; 0 where mask==0
__global__ __launch_bounds__(NTHREADS) void goalmap_kernel(
    const float* __restrict__ xL, const float* __restrict__ yL,
    const float* __restrict__ obj_list, const int* __restrict__ obj_num,
    const int* __restrict__ road_mask, float* __restrict__ out)
{
    constexpr float INV = 1.0f / (2.0f * 5.0f * 5.0f);  // SIGMA = 5.0

    __shared__ float ex_s[O_MAX * GRID_N];  // [o][h]
    __shared__ float ey_s[O_MAX * GRID_N];  // [o][w]
    __shared__ float gx_s[GRID_N];
    __shared__ float gy_s[GRID_N];

    const int b   = blockIdx.x;
    const int tid = threadIdx.x;
    const int n   = obj_num[b];      // wave-uniform per block, in [0, 48]
    const float xl = xL[b];
    const float yl = yL[b];

    // --- Stage 1: build 1-D gaussian tables in LDS ---
    for (int i = tid; i < GRID_N; i += NTHREADS) {
        float dx = (float)i - xl;
        float dy = (float)i - yl;
        gx_s[i] = __expf(-dx * dx * INV);
        gy_s[i] = __expf(-dy * dy * INV);
    }
    for (int i = tid; i < n * GRID_N; i += NTHREADS) {
        int o = i / GRID_N;
        int p = i - o * GRID_N;
        float xo = obj_list[(b * O_MAX + o) * 2 + 1];  // note: index 1 -> x (H dim)
        float yo = obj_list[(b * O_MAX + o) * 2 + 0];  // index 0 -> y (W dim)
        float dx = (float)p - xo;
        float dy = (float)p - yo;
        ex_s[i] = __expf(-dx * dx * INV);
        ey_s[i] = __expf(-dy * dy * INV);
    }
    __syncthreads();

    const int*  rm = road_mask + (size_t)b * HW_N;
    float*      op = out       + (size_t)b * HW_N;

    // --- Stage 2: each thread owns a 2(h) x 4(w) register tile ---
    const int NT = (GRID_N / 2) * (GRID_N / 4);  // 56 * 28 = 1568 tiles
    for (int t = tid; t < NT; t += NTHREADS) {
        int hp = t / 28;
        int wq = t - hp * 28;
        int h = hp * 2;
        int w = wq * 4;

        float4 acc0 = make_float4(0.f, 0.f, 0.f, 0.f);
        float4 acc1 = make_float4(0.f, 0.f, 0.f, 0.f);

        #pragma unroll 4
        for (int o = 0; o < n; ++o) {
            float  ea = ex_s[o * GRID_N + h];       // broadcast-ish
            float  eb = ex_s[o * GRID_N + h + 1];
            float4 ey = *(const float4*)&ey_s[o * GRID_N + w];  // ds_read_b128
            acc0.x = fmaf(ea, ey.x, acc0.x);
            acc0.y = fmaf(ea, ey.y, acc0.y);
            acc0.z = fmaf(ea, ey.z, acc0.z);
            acc0.w = fmaf(ea, ey.w, acc0.w);
            acc1.x = fmaf(eb, ey.x, acc1.x);
            acc1.y = fmaf(eb, ey.y, acc1.y);
            acc1.z = fmaf(eb, ey.z, acc1.z);
            acc1.w = fmaf(eb, ey.w, acc1.w);
        }

        float  gxa = gx_s[h];
        float  gxb = gx_s[h + 1];
        float4 gy4 = *(const float4*)&gy_s[w];

        int base0 = h * GRID_N + w;
        int base1 = base0 + GRID_N;
        int4 m0 = *(const int4*)&rm[base0];
        int4 m1 = *(const int4*)&rm[base1];

        float4 v0, v1;
        v0.x = 0.5f + 0.5f * (gxa * gy4.x - acc0.x);
        v0.y = 0.5f + 0.5f * (gxa * gy4.y - acc0.y);
        v0.z = 0.5f + 0.5f * (gxa * gy4.z - acc0.z);
        v0.w = 0.5f + 0.5f * (gxa * gy4.w - acc0.w);
        v1.x = 0.5f + 0.5f * (gxb * gy4.x - acc1.x);
        v1.y = 0.5f + 0.5f * (gxb * gy4.y - acc1.y);
        v1.z = 0.5f + 0.5f * (gxb * gy4.z - acc1.z);
        v1.w = 0.5f + 0.5f * (gxb * gy4.w - acc1.w);

        v0.x = (m0.x == 0) ? 0.f : v0.x;
        v0.y = (m0.y == 0) ? 0.f : v0.y;
        v0.z = (m0.z == 0) ? 0.f : v0.z;
        v0.w = (m0.w == 0) ? 0.f : v0.w;
        v1.x = (m1.x == 0) ? 0.f : v1.x;
        v1.y = (m1.y == 0) ? 0.f : v1.y;
        v1.z = (m1.z == 0) ? 0.f : v1.z;
        v1.w = (m1.w == 0) ? 0.f : v1.w;

        *(float4*)&op[base0] = v0;
        *(float4*)&op[base1] = v1;
    }
}

extern "C" void kernel_launch(void* const* d_in, const int* in_sizes, int n_in,
                              void* d_out, int out_size, void* d_ws, size_t ws_size,
                              hipStream_t stream) {
    const float* xL       = (const float*)d_in[0];
    const float* yL       = (const float*)d_in[1];
    const float* obj_list = (const float*)d_in[2];
    const int*   obj_num  = (const int*)d_in[3];
    const int*   road_mask= (const int*)d_in[4];
    float*       out      = (float*)d_out;
    const int B = in_sizes[0];  // 2048

    goalmap_kernel<<<B, NTHREADS, 0, stream>>>(xL, yL, obj_list, obj_num, road_mask, out);
}